// Round 1
// baseline (584.841 us; speedup 1.0000x reference)
//
#include <hip/hip_runtime.h>
#include <math.h>

namespace {
constexpr int kB    = 32;
constexpr int kMel  = 128;
constexpr int kT    = 8192;
constexpr int kKeys = 88;
constexpr int kTop  = 15;   // top[13] = 14th largest (s74), top[14] = 15th largest (s73)
}

__device__ __forceinline__ void top_insert(float (&top)[kTop], float v) {
#pragma unroll
  for (int j = 0; j < kTop; ++j) {
    const float hi = fmaxf(top[j], v);
    v = fminf(top[j], v);
    top[j] = hi;
  }
}

__global__ __launch_bounds__(256) void key_probs_kernel(
    const float* __restrict__ mel, const int* __restrict__ key_bins,
    float* __restrict__ out) {
  __shared__ int sbins[kKeys];
  const int tid = threadIdx.x;
  if (tid < kKeys) sbins[tid] = key_bins[tid];
  __syncthreads();

  const int t = blockIdx.x * 256 + tid;
  const int b = blockIdx.y;
  const float* melb = mel + (size_t)b * kMel * kT + t;

  // ---- pass 1: fast fp32 selection of 14th/15th largest --------------------
  float top[kTop];
#pragma unroll
  for (int j = 0; j < kTop; ++j) top[j] = 0.0f;

  for (int k = 0; k < kKeys; ++k) {
    const int m = __builtin_amdgcn_readfirstlane(sbins[k]);  // wave-uniform
    float v = expf(melb[(size_t)m * kT]);
    if (m < 64) v *= expf(melb[(size_t)(2 * m) * kT]);
    if (m < 43) v *= expf(melb[(size_t)(3 * m) * kT]);
    top_insert(top, v);
  }

  float s74 = top[13];
  const float s73 = top[14];
  // Ambiguous only if the rank-73/74 gap is within the exp-implementation
  // disagreement band (~few ulp). Includes gap==0 (possible fast-path tie of
  // truly-distinct inputs). Structural duplicate ties re-resolve identically.
  const bool amb = (s74 - s73) < 4e-6f * s74;

  if (amb) {  // rare (~1e-5 of columns): redo with correctly-rounded fp32 exp
    float tp[kTop];
#pragma unroll
    for (int j = 0; j < kTop; ++j) tp[j] = 0.0f;
    for (int k = 0; k < kKeys; ++k) {
      const int m = __builtin_amdgcn_readfirstlane(sbins[k]);
      float v = (float)::exp((double)melb[(size_t)m * kT]);
      if (m < 64) v *= (float)::exp((double)melb[(size_t)(2 * m) * kT]);
      if (m < 43) v *= (float)::exp((double)melb[(size_t)(3 * m) * kT]);
      top_insert(tp, v);
    }
    s74 = tp[13];
  }

  // ---- pass 2: recompute energies (cache-hot) and write both outputs -------
  float* o0 = out + (size_t)b * kKeys * kT + t;
  float* o1 = o0 + (size_t)kB * kKeys * kT;

  for (int k = 0; k < kKeys; ++k) {
    const int m = __builtin_amdgcn_readfirstlane(sbins[k]);
    float v;
    if (!amb) {
      v = expf(melb[(size_t)m * kT]);
      if (m < 64) v *= expf(melb[(size_t)(2 * m) * kT]);
      if (m < 43) v *= expf(melb[(size_t)(3 * m) * kT]);
    } else {
      v = (float)::exp((double)melb[(size_t)m * kT]);
      if (m < 64) v *= (float)::exp((double)melb[(size_t)(2 * m) * kT]);
      if (m < 43) v *= (float)::exp((double)melb[(size_t)(3 * m) * kT]);
    }
    const float r = (v >= s74) ? 1.0f : 0.0f;
    o0[(size_t)k * kT] = r;
    o1[(size_t)k * kT] = r;
  }
}

extern "C" void kernel_launch(void* const* d_in, const int* in_sizes, int n_in,
                              void* d_out, int out_size, void* d_ws, size_t ws_size,
                              hipStream_t stream) {
  const float* mel = (const float*)d_in[0];
  const int* key_bins = (const int*)d_in[1];
  float* out = (float*)d_out;
  dim3 grid(kT / 256, kB);
  key_probs_kernel<<<grid, dim3(256), 0, stream>>>(mel, key_bins, out);
}

// Round 2
// 378.450 us; speedup vs baseline: 1.5454x; 1.5454x over previous
//
#include <hip/hip_runtime.h>
#include <math.h>

namespace {
constexpr int kB    = 32;
constexpr int kMel  = 128;
constexpr int kT    = 8192;
constexpr int kKeys = 88;
constexpr int kTop  = 15;   // top[13] = 14th largest, top[14] = 15th largest
}

__device__ __forceinline__ void top_insert(float (&top)[kTop], float v) {
#pragma unroll
  for (int j = 0; j < kTop; ++j) {
    const float hi = fmaxf(top[j], v);
    v = fminf(top[j], v);
    top[j] = hi;
  }
}

__global__ __launch_bounds__(256, 4) void key_probs_kernel(
    const float* __restrict__ mel, const int* __restrict__ key_bins,
    float* __restrict__ out) {
  __shared__ int sbins[kKeys];
  const int tid = threadIdx.x;
  if (tid < kKeys) sbins[tid] = key_bins[tid];
  __syncthreads();

  const int t = blockIdx.x * 256 + tid;
  const int b = blockIdx.y;
  const float* melb = mel + (size_t)b * kMel * kT + t;

  // ---- phase A: gather log-domain sums (branchless, fully unrolled, max ILP)
  // e_k = exp(a)*exp(b)*exp(c) is monotone in s_k = a+b+c, so all ranking
  // happens on sums; no exp needed on the fast path.
  float s[kKeys];
#pragma unroll
  for (int k = 0; k < kKeys; ++k) {
    const int m = __builtin_amdgcn_readfirstlane(sbins[k]);  // wave-uniform
    const int r1 = (m < 64) ? 2 * m : m;   // dummy -> same row (L1-hot, in-bounds)
    const int r2 = (m < 43) ? 3 * m : m;
    const float w1 = (m < 64) ? 1.0f : 0.0f;
    const float w2 = (m < 43) ? 1.0f : 0.0f;
    const float v0 = melb[(size_t)m * kT];
    const float v1 = melb[(size_t)r1 * kT];
    const float v2 = melb[(size_t)r2 * kT];
    s[k] = v0 + w1 * v1 + w2 * v2;
  }

  // ---- phase B: select 14th/15th largest of the 88 sums ---------------------
  float top[kTop];
#pragma unroll
  for (int j = 0; j < kTop; ++j) top[j] = -1e30f;  // sums can be negative!
#pragma unroll
  for (int k = 0; k < kKeys; ++k) top_insert(top, s[k]);

  float r74 = top[13];
  // Only the rank-14/15 boundary gap matters: swaps internal to the top-14
  // set (or entirely below it) cannot change the >=thresh mask. Sum-space
  // abs gap < ~2.5e-6 is where product-space fp rounding could flip it.
  const bool amb = (top[13] - top[14]) < 1e-5f;

  if (amb) {  // rare: redo this lane in product space, np-compatible exp
    float tp[kTop];
#pragma unroll
    for (int j = 0; j < kTop; ++j) tp[j] = 0.0f;  // products are positive
#pragma unroll
    for (int k = 0; k < kKeys; ++k) {
      const int m = __builtin_amdgcn_readfirstlane(sbins[k]);
      float v = (float)::exp((double)melb[(size_t)m * kT]);
      if (m < 64) v *= (float)::exp((double)melb[(size_t)(2 * m) * kT]);
      if (m < 43) v *= (float)::exp((double)melb[(size_t)(3 * m) * kT]);
      s[k] = v;           // exec-masked: only amb lanes overwritten
      top_insert(tp, v);
    }
    r74 = tp[13];
  }

  // ---- phase C: classify + write both outputs -------------------------------
  float* o0 = out + (size_t)b * kKeys * kT + t;
  float* o1 = o0 + (size_t)kB * kKeys * kT;
#pragma unroll
  for (int k = 0; k < kKeys; ++k) {
    const float r = (s[k] >= r74) ? 1.0f : 0.0f;
    o0[(size_t)k * kT] = r;
    o1[(size_t)k * kT] = r;
  }
}

extern "C" void kernel_launch(void* const* d_in, const int* in_sizes, int n_in,
                              void* d_out, int out_size, void* d_ws, size_t ws_size,
                              hipStream_t stream) {
  const float* mel = (const float*)d_in[0];
  const int* key_bins = (const int*)d_in[1];
  float* out = (float*)d_out;
  dim3 grid(kT / 256, kB);
  key_probs_kernel<<<grid, dim3(256), 0, stream>>>(mel, key_bins, out);
}